// Round 9
// baseline (2762.774 us; speedup 1.0000x reference)
//
#include <hip/hip_runtime.h>
#include <hip/hip_bf16.h>

typedef __bf16 bf16x8 __attribute__((ext_vector_type(8)));
typedef float f32x4 __attribute__((ext_vector_type(4)));
typedef unsigned int u32;
typedef unsigned short u16;
typedef unsigned long long u64;

#define T_ 512
#define E_ 256
#define U_ 512

// ---------------- workspace layout (bytes) ----------------
// xs_g : bf16 [T][64][256] (granule-swizzled rows)                    16 MiB
// w2   : bf16 [2 d][8 us][8 wv][2 ct][24 j][64 lane][8] frag-ordered   6 MiB
// hpub : u32  [2 d][2 par][4 q][8 us][64 u][16 b]  (h<<16 | epoch)   512 KiB
// hfin : f32  [2][64][512] (plain)                                   256 KiB
static const size_t WS_XS = 0;
static const size_t WS_W2 = (size_t)16 << 20;
static const size_t WS_HP = WS_W2 + 6291456;
static const size_t WS_HF = WS_HP + 524288;

__device__ __forceinline__ float fsigm(float x) { return 1.f / (1.f + __expf(-x)); }
__device__ __forceinline__ float ftanh(float x) {
  float e = __expf(2.f * fabsf(x));
  float r = 1.f - 2.f / (e + 1.f);
  return copysignf(r, x);
}

// Embedding gather + bf16 convert + granule swizzle.
__global__ void embed_swz_kernel(const int* __restrict__ sent,
                                 const float* __restrict__ emb,
                                 __bf16* __restrict__ xs_g) {
  int id = blockIdx.x * 256 + threadIdx.x;
  int gx = id & 31;          // granule within row (32 x 8 bf16 = 256)
  int b  = (id >> 5) & 63;
  int t  = id >> 11;
  int idx = sent[b * T_ + t];            // sentence is [B][T]
  const float* src = emb + (size_t)idx * E_ + gx * 8;
  bf16x8 v;
#pragma unroll
  for (int j = 0; j < 8; ++j) v[j] = (__bf16)src[j];
  int gs = gx ^ (b & 7);                 // XOR swizzle keyed by batch row
  *(bf16x8*)(xs_g + (size_t)(t * 64 + b) * E_ + gs * 8) = v;
}

// Weight prep (fragment-ordered) + zero-init of hpub (epochs cleared every
// call so stale epochs from a previous replay can never match).
// 64-unit slices: tile = wv*2+ct covers z-cols c = tile*16 + (lane&15),
// c -> ul = tile*4 + ((lane&15)>>2), gate = (lane&15)&3.
__global__ void __launch_bounds__(256)
wprep_kernel(const float* __restrict__ Wx_f, const float* __restrict__ Wh_f,
             const float* __restrict__ Wx_b, const float* __restrict__ Wh_b,
             __bf16* __restrict__ w2, u32* __restrict__ hpub) {
  int bid = blockIdx.x;              // ((((d*8+us)*8+wv)*2+ct)*6 + jg
  int tid = threadIdx.x;
  {
    int zid = bid * 256 + tid;
    if (zid < 131072) hpub[zid] = 0u;
  }
  int jg = bid % 6;
  int ct = (bid / 6) & 1;
  int wv = (bid / 12) & 7;
  int us = (bid / 96) & 7;
  int d  = bid / 768;
  int j    = jg * 4 + (tid >> 6);
  int lane = tid & 63;
  int r    = lane & 15;
  int tile = wv * 2 + ct;
  int ul   = tile * 4 + (r >> 2);
  int gate = r & 3;
  int n    = gate * 512 + us * 64 + ul;
  int k0   = j * 32 + (lane >> 4) * 8;
  const float* Wx = d ? Wx_b : Wx_f;
  const float* Wh = d ? Wh_b : Wh_f;
  bf16x8 v;
#pragma unroll
  for (int e = 0; e < 8; ++e) {
    int k = k0 + e;
    float f = (k < 256) ? Wx[(size_t)k * 2048 + n] : Wh[(size_t)(k - 256) * 2048 + n];
    v[e] = (__bf16)f;
  }
  size_t og = ((size_t)(((d * 8 + us) * 8 + wv) * 2 + ct) * 24 + j) * 64 + lane;
  *(bf16x8*)(w2 + og * 8) = v;
}

// Persistent bidirectional LSTM. 64 WGs x 512 thr (8 waves).
// WG = (dir, us 0..7, q 0..3): 64 units x 16 batches. Fan-in 8.
// Thread owns 2 (unit,batch) pairs: ul = wv*8 + ct*4 + kq, b = q*16 + bq_l.
// hpub slice word = us*1024 + u*16 + b, value (bf16 h)<<16 | epoch16.
// Step: spec-load 8 u64 -> x-MFMAs -> {validate half, pack, bar, h-MFMAs} x2
// -> gates x2 -> publish 2 words -> stage x -> bar.
__global__ void __launch_bounds__(512, 2)
lstm_main(const __bf16* __restrict__ xs_g, const __bf16* __restrict__ w2,
          u32* __restrict__ hpub, float* __restrict__ hfin,
          const float* __restrict__ b_f, const float* __restrict__ b_b) {
  __shared__ __align__(16) __bf16 xbuf[2][16 * 256];   // 2 x 8 KiB
  __shared__ __align__(16) __bf16 hbuf[16 * 512];      // 16 KiB

  const int wg   = blockIdx.x;
  const int dir  = wg >> 5;
  const int sl   = wg & 31;
  const int us   = sl >> 2;            // 0..7
  const int q    = sl & 3;
  const int tid  = threadIdx.x;
  const int wv   = tid >> 6;           // 0..7
  const int lane = tid & 63;
  const int bq_l = lane & 15;          // local batch / D col
  const int kq   = lane >> 4;          // k-quarter
  const int bsw  = bq_l & 7;           // swizzle key
  const int b_own  = q * 16 + bq_l;

  // ---- weight fragments: direct coalesced global->reg (48 x bf16x8) ----
  bf16x8 wfrag[48];                    // [ct][j]
  {
    const bf16x8* wp = (const bf16x8*)w2 +
                       ((size_t)((dir * 8 + us) * 8 + wv) * 48) * 64 + lane;
#pragma unroll
    for (int j = 0; j < 48; ++j) wfrag[j] = wp[j * 64];
  }

  const float* bias = dir ? b_b : b_f;
  float bi[2], bff[2], bg[2], bo[2], c_st[2];
  int u_own[2];
#pragma unroll
  for (int ct = 0; ct < 2; ++ct) {
    u_own[ct] = us * 64 + (wv * 2 + ct) * 4 + kq;
    bi[ct]  = bias[u_own[ct]];
    bff[ct] = bias[512 + u_own[ct]];
    bg[ct]  = bias[1024 + u_own[ct]];
    bo[ct]  = bias[1536 + u_own[ct]];
    c_st[ct] = 0.f;
  }

  // ---- producer word ptrs: word = us*1024 + wv*128 + ct*64 + lane ----
  u32* const pw0 = hpub + ((size_t)(dir * 2 + 0) * 4 + q) * 8192 +
                   us * 1024 + wv * 128 + lane;

  // ---- consumer mapping: half H -> producer p=H*4+ph, 4 consecutive u ----
  const int ph   = tid >> 7;           // 0..3
  const int inr  = tid & 127;
  const int b2   = inr & 7;            // batch pair (2*b2, 2*b2+1)
  const int u0g  = inr >> 3;           // 0..15
  const int u0   = u0g * 4;            // 0..60 within producer's 64 units
  const u64* const cb = (const u64*)hpub + ((size_t)(dir * 2 + 0) * 4 + q) * 4096;
  // LDS pack dests (per half H): units (H*4+ph)*64 + u0 .. +3, batches 2b2(+1)
  const int be = 2 * b2, bo_ = 2 * b2 + 1;
  int cde[2], cdo[2];
#pragma unroll
  for (int H = 0; H < 2; ++H) {
    int g0  = (H * 4 + ph) * 8 + (u0g >> 1);   // 8-unit granule 0..63
    int off = (u0g & 1) * 8;
    cde[H] = be  * 1024 + ((g0 ^ (be  & 7)) << 4) + off;
    cdo[H] = bo_ * 1024 + ((g0 ^ (bo_ & 7)) << 4) + off;
  }

  // ---- stage x_0 (8 KiB: 512 granules, 1 per thread) ----
  {
    int t0 = dir ? (T_ - 1) : 0;
    const uint4* xsrc = (const uint4*)(xs_g + ((size_t)t0 * 64 + q * 16) * 256);
    ((uint4*)xbuf[0])[tid] = xsrc[tid];
  }
  __syncthreads();

  for (int t = 0;; ++t) {
    const bool lastt = (t == T_ - 1);
    // ---- [P] speculative coalesced h loads (8 u64/thread, both halves) ----
    u64 v[8];
    const u64* csrc = cb + (size_t)(t & 1) * 16384;
    if (t > 0) {
#pragma unroll
      for (int H = 0; H < 2; ++H)
#pragma unroll
        for (int du = 0; du < 4; ++du)
          v[H * 4 + du] = __hip_atomic_load(
              csrc + (H * 4 + ph) * 512 + (u0 + du) * 8 + b2,
              __ATOMIC_RELAXED, __HIP_MEMORY_SCOPE_AGENT);
    }
    // ---- issue x_{t+1} global load early ----
    uint4 xg;
    if (!lastt) {
      const int teff = dir ? (T_ - 2 - t) : (t + 1);
      xg = ((const uint4*)(xs_g + ((size_t)teff * 64 + q * 16) * 256))[tid];
    }

    // ---- [A] x-part MFMAs (hide h flight) ----
    f32x4 acc0[2], acc1[2];
#pragma unroll
    for (int ct = 0; ct < 2; ++ct) {
      acc0[ct] = (f32x4){0.f, 0.f, 0.f, 0.f};
      acc1[ct] = (f32x4){0.f, 0.f, 0.f, 0.f};
    }
    const __bf16* xb = xbuf[t & 1];
#pragma unroll
    for (int j = 0; j < 8; ++j) {
      int g = j * 4 + kq;
      bf16x8 a = *(const bf16x8*)(xb + bq_l * 256 + ((g ^ bsw) << 3));
      if (j & 1) {
        acc1[0] = __builtin_amdgcn_mfma_f32_16x16x32_bf16(wfrag[j], a, acc1[0], 0, 0, 0);
        acc1[1] = __builtin_amdgcn_mfma_f32_16x16x32_bf16(wfrag[24 + j], a, acc1[1], 0, 0, 0);
      } else {
        acc0[0] = __builtin_amdgcn_mfma_f32_16x16x32_bf16(wfrag[j], a, acc0[0], 0, 0, 0);
        acc0[1] = __builtin_amdgcn_mfma_f32_16x16x32_bf16(wfrag[24 + j], a, acc0[1], 0, 0, 0);
      }
    }

    if (t > 0) {
      const u32 ep = (u32)t;
      // ==== half 1: producers 0..3 (units 0..255, j=0..7) ====
      for (;;) {
        u32 bad = 0;
#pragma unroll
        for (int j = 0; j < 4; ++j)
          bad |= ((u32)v[j] ^ ep) | ((u32)(v[j] >> 32) ^ ep);
        bad &= 0xFFFFu;
        if (!__any((int)bad)) break;
        __builtin_amdgcn_s_sleep(1);
#pragma unroll
        for (int du = 0; du < 4; ++du)
          v[du] = __hip_atomic_load(csrc + ph * 512 + (u0 + du) * 8 + b2,
                                    __ATOMIC_RELAXED, __HIP_MEMORY_SCOPE_AGENT);
      }
      {
        u64 we = 0, wo = 0;
#pragma unroll
        for (int du = 0; du < 4; ++du) {
          u64 x = v[du];
          we |= (u64)((u32)(x >> 16) & 0xFFFFu) << (16 * du);
          wo |= (u64)((u32)(x >> 48) & 0xFFFFu) << (16 * du);
        }
        *(u64*)((char*)hbuf + cde[0]) = we;
        *(u64*)((char*)hbuf + cdo[0]) = wo;
      }
      __syncthreads();   // S1: half-1 staged
#pragma unroll
      for (int j = 0; j < 8; ++j) {
        int g = j * 4 + kq;
        bf16x8 a = *(const bf16x8*)(hbuf + bq_l * 512 + ((g ^ bsw) << 3));
        if (j & 1) {
          acc1[0] = __builtin_amdgcn_mfma_f32_16x16x32_bf16(wfrag[8 + j], a, acc1[0], 0, 0, 0);
          acc1[1] = __builtin_amdgcn_mfma_f32_16x16x32_bf16(wfrag[32 + j], a, acc1[1], 0, 0, 0);
        } else {
          acc0[0] = __builtin_amdgcn_mfma_f32_16x16x32_bf16(wfrag[8 + j], a, acc0[0], 0, 0, 0);
          acc0[1] = __builtin_amdgcn_mfma_f32_16x16x32_bf16(wfrag[32 + j], a, acc0[1], 0, 0, 0);
        }
      }
      // ==== half 2: producers 4..7 (units 256..511, j=8..15) ====
      for (;;) {
        u32 bad = 0;
#pragma unroll
        for (int j = 4; j < 8; ++j)
          bad |= ((u32)v[j] ^ ep) | ((u32)(v[j] >> 32) ^ ep);
        bad &= 0xFFFFu;
        if (!__any((int)bad)) break;
        __builtin_amdgcn_s_sleep(1);
#pragma unroll
        for (int du = 0; du < 4; ++du)
          v[4 + du] = __hip_atomic_load(csrc + (4 + ph) * 512 + (u0 + du) * 8 + b2,
                                        __ATOMIC_RELAXED, __HIP_MEMORY_SCOPE_AGENT);
      }
      {
        u64 we = 0, wo = 0;
#pragma unroll
        for (int du = 0; du < 4; ++du) {
          u64 x = v[4 + du];
          we |= (u64)((u32)(x >> 16) & 0xFFFFu) << (16 * du);
          wo |= (u64)((u32)(x >> 48) & 0xFFFFu) << (16 * du);
        }
        *(u64*)((char*)hbuf + cde[1]) = we;
        *(u64*)((char*)hbuf + cdo[1]) = wo;
      }
      __syncthreads();   // S2: half-2 staged
#pragma unroll
      for (int j = 8; j < 16; ++j) {
        int g = j * 4 + kq;
        bf16x8 a = *(const bf16x8*)(hbuf + bq_l * 512 + ((g ^ bsw) << 3));
        if (j & 1) {
          acc1[0] = __builtin_amdgcn_mfma_f32_16x16x32_bf16(wfrag[8 + j], a, acc1[0], 0, 0, 0);
          acc1[1] = __builtin_amdgcn_mfma_f32_16x16x32_bf16(wfrag[32 + j], a, acc1[1], 0, 0, 0);
        } else {
          acc0[0] = __builtin_amdgcn_mfma_f32_16x16x32_bf16(wfrag[8 + j], a, acc0[0], 0, 0, 0);
          acc0[1] = __builtin_amdgcn_mfma_f32_16x16x32_bf16(wfrag[32 + j], a, acc0[1], 0, 0, 0);
        }
      }
    }

    // ---- gates in registers (2 (unit,batch) pairs) ----
#pragma unroll
    for (int ct = 0; ct < 2; ++ct) {
      const float zi = acc0[ct][0] + acc1[ct][0] + bi[ct];
      const float zf = acc0[ct][1] + acc1[ct][1] + bff[ct];
      const float zg = acc0[ct][2] + acc1[ct][2] + bg[ct];
      const float zo = acc0[ct][3] + acc1[ct][3] + bo[ct];
      c_st[ct] = fsigm(zf) * c_st[ct] + fsigm(zi) * ftanh(zg);
      const float hv = fsigm(zo) * ftanh(c_st[ct]);
      if (lastt) {
        hfin[(size_t)dir * 32768 + b_own * 512 + u_own[ct]] = hv;
      } else {
        union { __bf16 h; u16 s; } cv;
        cv.h = (__bf16)hv;
        u32 word = ((u32)cv.s << 16) | (u32)(t + 1);
        __hip_atomic_store(pw0 + ((t + 1) & 1) * 32768 + ct * 64, word,
                           __ATOMIC_RELAXED, __HIP_MEMORY_SCOPE_AGENT);
      }
    }
    if (lastt) break;

    // ---- stage x_{t+1} (load already in flight) ----
    ((uint4*)xbuf[(t + 1) & 1])[tid] = xg;
    __syncthreads();   // S3: xbuf ready; hbuf reads done
  }
}

// Final head: out = sigmoid((hcat @ W1 + b1) @ W2 + b2), all f32. One block.
__global__ void __launch_bounds__(1024)
dense_kernel(const float* __restrict__ hfin, const float* __restrict__ W1,
             const float* __restrict__ b1, const float* __restrict__ W2,
             const float* __restrict__ b2, float* __restrict__ out) {
  __shared__ float hid[64][64];
  const int t = threadIdx.x;
  const int b = t >> 4;
  const int jg = t & 15;           // 4 output cols each
  float a0 = b1[jg * 4 + 0], a1 = b1[jg * 4 + 1], a2 = b1[jg * 4 + 2], a3 = b1[jg * 4 + 3];
#pragma unroll 8
  for (int k = 0; k < 1024; ++k) {
    const float hv = hfin[(size_t)(k >> 9) * 32768 + b * 512 + (k & 511)];
    const float4 w = *(const float4*)(W1 + (size_t)k * 64 + jg * 4);
    a0 += hv * w.x; a1 += hv * w.y; a2 += hv * w.z; a3 += hv * w.w;
  }
  hid[b][jg * 4 + 0] = a0; hid[b][jg * 4 + 1] = a1;
  hid[b][jg * 4 + 2] = a2; hid[b][jg * 4 + 3] = a3;
  __syncthreads();
  if (t < 64) {
    float l = b2[0];
#pragma unroll 8
    for (int j = 0; j < 64; ++j) l += hid[t][j] * W2[j];
    out[t] = 1.f / (1.f + __expf(-l));
  }
}

extern "C" void kernel_launch(void* const* d_in, const int* in_sizes, int n_in,
                              void* d_out, int out_size, void* d_ws, size_t ws_size,
                              hipStream_t stream) {
  const int*   sent = (const int*)d_in[0];
  const float* emb  = (const float*)d_in[1];
  const float* Wx_f = (const float*)d_in[2];
  const float* Wh_f = (const float*)d_in[3];
  const float* b_f  = (const float*)d_in[4];
  const float* Wx_b = (const float*)d_in[5];
  const float* Wh_b = (const float*)d_in[6];
  const float* b_b  = (const float*)d_in[7];
  const float* W1   = (const float*)d_in[8];
  const float* b1   = (const float*)d_in[9];
  const float* W2   = (const float*)d_in[10];
  const float* b2   = (const float*)d_in[11];
  float* out = (float*)d_out;

  char* ws = (char*)d_ws;
  __bf16* xs_g = (__bf16*)(ws + WS_XS);
  __bf16* w2   = (__bf16*)(ws + WS_W2);
  u32*    hpub = (u32*)(ws + WS_HP);
  float*  hfin = (float*)(ws + WS_HF);

  hipLaunchKernelGGL(embed_swz_kernel, dim3(4096), dim3(256), 0, stream, sent, emb, xs_g);
  hipLaunchKernelGGL(wprep_kernel, dim3(1536), dim3(256), 0, stream,
                     Wx_f, Wh_f, Wx_b, Wh_b, w2, hpub);

  void* args[] = {(void*)&xs_g, (void*)&w2, (void*)&hpub, (void*)&hfin,
                  (void*)&b_f, (void*)&b_b};
  hipLaunchCooperativeKernel((void*)lstm_main, dim3(64), dim3(512), args, 0, stream);

  hipLaunchKernelGGL(dense_kernel, dim3(1), dim3(1024), 0, stream,
                     hfin, W1, b1, W2, b2, out);
}

// Round 11
// 1619.680 us; speedup vs baseline: 1.7058x; 1.7058x over previous
//
#include <hip/hip_runtime.h>
#include <hip/hip_bf16.h>

typedef __bf16 bf16x8 __attribute__((ext_vector_type(8)));
typedef float f32x4 __attribute__((ext_vector_type(4)));
typedef unsigned int u32;
typedef unsigned short u16;
typedef unsigned long long u64;

#define T_ 512
#define E_ 256
#define U_ 512

// ---------------- workspace layout (bytes) ----------------
// xs_g : bf16 [T][64][256] (granule-swizzled rows)                 16 MiB
// w2   : bf16 [2 dir][16 us][8 wv][24 j][64 lane][8] frag-ordered   6 MiB
// hpub : u32  [2 dir][2 par][4 q][16 us][32 u][16 b] (h<<16|ep)   512 KiB
// hfin : f32  [2][64][512] (plain)                                256 KiB
static const size_t WS_XS = 0;
static const size_t WS_W2 = (size_t)16 << 20;
static const size_t WS_HP = WS_W2 + 6291456;
static const size_t WS_HF = WS_HP + 524288;

__device__ __forceinline__ float fsigm(float x) { return 1.f / (1.f + __expf(-x)); }
__device__ __forceinline__ float ftanh(float x) {
  float e = __expf(2.f * fabsf(x));
  float r = 1.f - 2.f / (e + 1.f);
  return copysignf(r, x);
}

// Embedding gather + bf16 convert + granule swizzle.
__global__ void embed_swz_kernel(const int* __restrict__ sent,
                                 const float* __restrict__ emb,
                                 __bf16* __restrict__ xs_g) {
  int id = blockIdx.x * 256 + threadIdx.x;
  int gx = id & 31;          // granule within row (32 x 8 bf16 = 256)
  int b  = (id >> 5) & 63;
  int t  = id >> 11;
  int idx = sent[b * T_ + t];            // sentence is [B][T]
  const float* src = emb + (size_t)idx * E_ + gx * 8;
  bf16x8 v;
#pragma unroll
  for (int j = 0; j < 8; ++j) v[j] = (__bf16)src[j];
  int gs = gx ^ (b & 7);                 // XOR swizzle keyed by batch row
  *(bf16x8*)(xs_g + (size_t)(t * 64 + b) * E_ + gs * 8) = v;
}

// Weight prep (fragment-ordered for direct coalesced global->reg in lstm_main)
// + zero-init of the self-validating h publication buffer (epochs cleared —
// required every call so stale epochs from a previous replay can never match).
__global__ void __launch_bounds__(256)
wprep_kernel(const float* __restrict__ Wx_f, const float* __restrict__ Wh_f,
             const float* __restrict__ Wx_b, const float* __restrict__ Wh_b,
             __bf16* __restrict__ w2, u32* __restrict__ hpub) {
  int bid = blockIdx.x;              // ((d*16+us)*8+wv)*6 + jg
  int tid = threadIdx.x;
  {
    int zid = bid * 256 + tid;
    if (zid < 131072) hpub[zid] = 0u;
  }
  int jg = bid % 6;
  int wv = (bid / 6) & 7;
  int us = (bid / 48) & 15;
  int d  = bid / 768;
  int j    = jg * 4 + (tid >> 6);
  int lane = tid & 63;
  int c    = wv * 16 + (lane & 15);   // slice row 0..127
  int ul   = c >> 2, gate = c & 3;
  int n    = gate * 512 + us * 32 + ul;
  int k0   = j * 32 + (lane >> 4) * 8;
  const float* Wx = d ? Wx_b : Wx_f;
  const float* Wh = d ? Wh_b : Wh_f;
  bf16x8 v;
#pragma unroll
  for (int e = 0; e < 8; ++e) {
    int k = k0 + e;
    float f = (k < 256) ? Wx[(size_t)k * 2048 + n] : Wh[(size_t)(k - 256) * 2048 + n];
    v[e] = (__bf16)f;
  }
  size_t og = ((size_t)((d * 16 + us) * 8 + wv) * 24 + j) * 64 + lane;
  *(bf16x8*)(w2 + og * 8) = v;
}

// Persistent bidirectional LSTM. 128 WGs x 512 thr.
// WG = (dir, us 0..15, q 0..3): units 32us..+31, batches 16q..+15.
// ONE raw s_barrier per step (lgkmcnt-only wait); publish stores and the
// 2-step-ahead x prefetch stay in flight across it. hbuf parity-double-
// buffered; xbuf is a 4-deep ring (write@t of x(t+2), read@t of x(t)).
__global__ void __launch_bounds__(512)
lstm_main(const __bf16* __restrict__ xs_g, const __bf16* __restrict__ w2,
          u32* __restrict__ hpub, float* __restrict__ hfin,
          const float* __restrict__ b_f, const float* __restrict__ b_b) {
  __shared__ __align__(16) __bf16 xbuf[4][16 * 256];   // 4 x 8 KiB ring
  __shared__ __align__(16) __bf16 hbuf[2][16 * 512];   // 2 x 16 KiB (parity)

  const int wg   = blockIdx.x;
  const int dir  = wg >> 6;
  const int sl   = wg & 63;
  const int us   = sl >> 2;
  const int q    = sl & 3;
  const int tid  = threadIdx.x;
  const int wv   = tid >> 6;
  const int lane = tid & 63;
  const int bq_l = lane & 15;          // local batch / D col
  const int kq   = lane >> 4;          // k-quarter
  const int bsw  = bq_l & 7;           // swizzle key
  const int ul_own = wv * 4 + kq;      // owned local unit (0..31)
  const int u_own  = us * 32 + ul_own;
  const int b_own  = q * 16 + bq_l;

  // ---- weight fragments: direct coalesced global->reg ----
  bf16x8 wfrag[24];
  {
    const bf16x8* wp = (const bf16x8*)w2 +
                       ((size_t)((dir * 16 + us) * 8 + wv) * 24) * 64 + lane;
#pragma unroll
    for (int j = 0; j < 24; ++j) wfrag[j] = wp[j * 64];
  }

  const float* bias = dir ? b_b : b_f;
  const float bi  = bias[u_own];
  const float bff = bias[512 + u_own];
  const float bg  = bias[1024 + u_own];
  const float bo  = bias[1536 + u_own];
  float c_st = 0.f;

  // ---- producer word ptr: slice stride 512 words ([32 u][16 b]) ----
  // word = ul_own*16 + bq_l = wv*64 + lane   (FIX vs r10: us stride 512)
  u32* const pw0 = hpub + ((size_t)((dir * 2 + 0) * 64 + q * 16 + us)) * 512 +
                   wv * 64 + lane;

  // ---- consumer: half-wave covers producer us_p's 2KB slice ----
  const int us_p  = 2 * wv + (lane >> 5);
  const int lane5 = lane & 31;
  const u64* const cs0 = (const u64*)(hpub + ((size_t)((dir * 2 + 0) * 64 + q * 16 + us_p)) * 512) + lane5;
  const u64* const cs1 = cs0 + 16384;   // parity stride = 32768 u32 = 16384 u64
  // u64 j covers words (u = us_p*32 + j*4 + (lane5>>3), b = 2*(lane5&7), +1)
  const int cc = lane5 >> 3;
  const int cb0 = 2 * (lane5 & 7);
  const int cb1 = cb0 + 1;
  int cd0[8], cd1[8];
#pragma unroll
  for (int j = 0; j < 8; ++j) {
    int u = us_p * 32 + j * 4 + cc;    // global unit within quarter's 512
    int g = u >> 3;
    cd0[j] = cb0 * 1024 + ((g ^ (cb0 & 7)) << 4) + ((u & 7) << 1);
    cd1[j] = cb1 * 1024 + ((g ^ (cb1 & 7)) << 4) + ((u & 7) << 1);
  }

  // ---- prologue: stage x(0), x(1); issue x(2) into carried register ----
  {
    int te0 = dir ? (T_ - 1) : 0;
    int te1 = dir ? (T_ - 2) : 1;
    ((uint4*)xbuf[0])[tid] = ((const uint4*)(xs_g + ((size_t)te0 * 64 + q * 16) * 256))[tid];
    ((uint4*)xbuf[1])[tid] = ((const uint4*)(xs_g + ((size_t)te1 * 64 + q * 16) * 256))[tid];
  }
  __syncthreads();
  uint4 xg;
  {
    int te2 = dir ? (T_ - 3) : 2;
    xg = ((const uint4*)(xs_g + ((size_t)te2 * 64 + q * 16) * 256))[tid];
  }

  for (int t = 0;; ++t) {
    const bool lastt = (t == T_ - 1);
    // ---- [P] speculative coalesced h loads (issued first) ----
    u64 v[8];
    const u64* csrc = (t & 1) ? cs1 : cs0;
    if (t > 0) {
#pragma unroll
      for (int j = 0; j < 8; ++j)
        v[j] = __hip_atomic_load(csrc + j * 32, __ATOMIC_RELAXED, __HIP_MEMORY_SCOPE_AGENT);
    }

    // ---- [A] x-part MFMAs (read xbuf ring slot t&3) ----
    f32x4 acc0 = {0.f, 0.f, 0.f, 0.f};
    f32x4 acc1 = {0.f, 0.f, 0.f, 0.f};
    const __bf16* xb = xbuf[t & 3];
#pragma unroll
    for (int j = 0; j < 8; ++j) {
      int g = j * 4 + kq;
      bf16x8 a = *(const bf16x8*)(xb + bq_l * 256 + ((g ^ bsw) << 3));
      if (j & 1) acc1 = __builtin_amdgcn_mfma_f32_16x16x32_bf16(wfrag[j], a, acc1, 0, 0, 0);
      else       acc0 = __builtin_amdgcn_mfma_f32_16x16x32_bf16(wfrag[j], a, acc0, 0, 0, 0);
    }

    // ---- x-stage: write carried x(t+2) (landed long ago); issue x(t+3) ----
    ((uint4*)xbuf[(t + 2) & 3])[tid] = xg;
    {
      int tn = (t + 3 < T_) ? (t + 3) : (T_ - 1);
      int te = dir ? (T_ - 1 - tn) : tn;
      xg = ((const uint4*)(xs_g + ((size_t)te * 64 + q * 16) * 256))[tid];
    }

    if (t > 0) {
      // ---- [B] validate embedded epochs; retry until fresh ----
      const u32 ep = (u32)t;
      for (;;) {
        u32 bad = 0;
#pragma unroll
        for (int j = 0; j < 8; ++j)
          bad |= ((u32)v[j] ^ ep) | ((u32)(v[j] >> 32) ^ ep);
        bad &= 0xFFFFu;
        if (!__any((int)bad)) break;
        __builtin_amdgcn_s_sleep(1);
#pragma unroll
        for (int j = 0; j < 8; ++j)
          v[j] = __hip_atomic_load(csrc + j * 32, __ATOMIC_RELAXED, __HIP_MEMORY_SCOPE_AGENT);
      }
      // ---- [C] pack hi16s -> swizzled hbuf[t&1] (16 x ds_write_b16) ----
      char* hb = (char*)hbuf[t & 1];
#pragma unroll
      for (int j = 0; j < 8; ++j) {
        *(u16*)(hb + cd0[j]) = (u16)(v[j] >> 16);
        *(u16*)(hb + cd1[j]) = (u16)(v[j] >> 48);
      }
    }

    // ---- single raw barrier: LDS-only drain; VMEM stays in flight ----
    asm volatile("s_waitcnt lgkmcnt(0)" ::: "memory");
    __builtin_amdgcn_sched_barrier(0);
    __builtin_amdgcn_s_barrier();
    __builtin_amdgcn_sched_barrier(0);

    if (t > 0) {
      // ---- [D] h-part MFMAs ----
      const __bf16* hb = hbuf[t & 1];
#pragma unroll
      for (int j = 0; j < 16; ++j) {
        int g = j * 4 + kq;
        bf16x8 a = *(const bf16x8*)(hb + bq_l * 512 + ((g ^ bsw) << 3));
        if (j & 1) acc1 = __builtin_amdgcn_mfma_f32_16x16x32_bf16(wfrag[8 + j], a, acc1, 0, 0, 0);
        else       acc0 = __builtin_amdgcn_mfma_f32_16x16x32_bf16(wfrag[8 + j], a, acc0, 0, 0, 0);
      }
    }

    // ---- gates in registers ----
    const float zi = acc0[0] + acc1[0] + bi;
    const float zf = acc0[1] + acc1[1] + bff;
    const float zg = acc0[2] + acc1[2] + bg;
    const float zo = acc0[3] + acc1[3] + bo;
    c_st = fsigm(zf) * c_st + fsigm(zi) * ftanh(zg);
    const float hv = fsigm(zo) * ftanh(c_st);

    if (lastt) {
      hfin[(size_t)dir * 32768 + b_own * 512 + u_own] = hv;
      break;
    }

    // ---- [E] publish own word (coalesced, fire-and-forget, no ack) ----
    {
      union { __bf16 h; u16 s; } cv;
      cv.h = (__bf16)hv;
      u32 word = ((u32)cv.s << 16) | (u32)(t + 1);
      __hip_atomic_store(pw0 + ((t + 1) & 1) * 32768, word, __ATOMIC_RELAXED,
                         __HIP_MEMORY_SCOPE_AGENT);
    }
  }
}

// Final head: out = sigmoid((hcat @ W1 + b1) @ W2 + b2), all f32. One block.
__global__ void __launch_bounds__(1024)
dense_kernel(const float* __restrict__ hfin, const float* __restrict__ W1,
             const float* __restrict__ b1, const float* __restrict__ W2,
             const float* __restrict__ b2, float* __restrict__ out) {
  __shared__ float hid[64][64];
  const int t = threadIdx.x;
  const int b = t >> 4;
  const int jg = t & 15;           // 4 output cols each
  float a0 = b1[jg * 4 + 0], a1 = b1[jg * 4 + 1], a2 = b1[jg * 4 + 2], a3 = b1[jg * 4 + 3];
#pragma unroll 8
  for (int k = 0; k < 1024; ++k) {
    const float hv = hfin[(size_t)(k >> 9) * 32768 + b * 512 + (k & 511)];
    const float4 w = *(const float4*)(W1 + (size_t)k * 64 + jg * 4);
    a0 += hv * w.x; a1 += hv * w.y; a2 += hv * w.z; a3 += hv * w.w;
  }
  hid[b][jg * 4 + 0] = a0; hid[b][jg * 4 + 1] = a1;
  hid[b][jg * 4 + 2] = a2; hid[b][jg * 4 + 3] = a3;
  __syncthreads();
  if (t < 64) {
    float l = b2[0];
#pragma unroll 8
    for (int j = 0; j < 64; ++j) l += hid[t][j] * W2[j];
    out[t] = 1.f / (1.f + __expf(-l));
  }
}

extern "C" void kernel_launch(void* const* d_in, const int* in_sizes, int n_in,
                              void* d_out, int out_size, void* d_ws, size_t ws_size,
                              hipStream_t stream) {
  const int*   sent = (const int*)d_in[0];
  const float* emb  = (const float*)d_in[1];
  const float* Wx_f = (const float*)d_in[2];
  const float* Wh_f = (const float*)d_in[3];
  const float* b_f  = (const float*)d_in[4];
  const float* Wx_b = (const float*)d_in[5];
  const float* Wh_b = (const float*)d_in[6];
  const float* b_b  = (const float*)d_in[7];
  const float* W1   = (const float*)d_in[8];
  const float* b1   = (const float*)d_in[9];
  const float* W2   = (const float*)d_in[10];
  const float* b2   = (const float*)d_in[11];
  float* out = (float*)d_out;

  char* ws = (char*)d_ws;
  __bf16* xs_g = (__bf16*)(ws + WS_XS);
  __bf16* w2   = (__bf16*)(ws + WS_W2);
  u32*    hpub = (u32*)(ws + WS_HP);
  float*  hfin = (float*)(ws + WS_HF);

  hipLaunchKernelGGL(embed_swz_kernel, dim3(4096), dim3(256), 0, stream, sent, emb, xs_g);
  hipLaunchKernelGGL(wprep_kernel, dim3(1536), dim3(256), 0, stream,
                     Wx_f, Wh_f, Wx_b, Wh_b, w2, hpub);

  void* args[] = {(void*)&xs_g, (void*)&w2, (void*)&hpub, (void*)&hfin,
                  (void*)&b_f, (void*)&b_b};
  hipLaunchCooperativeKernel((void*)lstm_main, dim3(128), dim3(512), args, 0, stream);

  hipLaunchKernelGGL(dense_kernel, dim3(1), dim3(1024), 0, stream,
                     hfin, W1, b1, W2, b2, out);
}

// Round 12
// 1082.947 us; speedup vs baseline: 2.5512x; 1.4956x over previous
//
#include <hip/hip_runtime.h>
#include <hip/hip_bf16.h>

typedef __bf16 bf16x8 __attribute__((ext_vector_type(8)));
typedef float f32x4 __attribute__((ext_vector_type(4)));
typedef unsigned int u32;
typedef unsigned short u16;
typedef unsigned long long u64;

#define T_ 512
#define E_ 256
#define U_ 512

// ---------------- workspace layout (bytes) ----------------
// xs_g : bf16 [T][64][256] (granule-swizzled rows)                 16 MiB
// w2   : bf16 [2 dir][16 us][8 wv][24 j][64 lane][8] frag-ordered   6 MiB
// hpub : u32  [2 dir][2 par][4 q][16 us][32 u][16 b] (h<<16|ep)   512 KiB
// hfin : f32  [2][64][512] (plain)                                256 KiB
static const size_t WS_XS = 0;
static const size_t WS_W2 = (size_t)16 << 20;
static const size_t WS_HP = WS_W2 + 6291456;
static const size_t WS_HF = WS_HP + 524288;

__device__ __forceinline__ float fsigm(float x) { return 1.f / (1.f + __expf(-x)); }
__device__ __forceinline__ float ftanh(float x) {
  float e = __expf(2.f * fabsf(x));
  float r = 1.f - 2.f / (e + 1.f);
  return copysignf(r, x);
}

// Merged prep: blocks [0,4096) = embedding gather+swizzle;
// blocks [4096,5632) = weight fragment layout + hpub epoch clear.
__global__ void __launch_bounds__(256)
prep_kernel(const int* __restrict__ sent, const float* __restrict__ emb,
            __bf16* __restrict__ xs_g,
            const float* __restrict__ Wx_f, const float* __restrict__ Wh_f,
            const float* __restrict__ Wx_b, const float* __restrict__ Wh_b,
            __bf16* __restrict__ w2, u32* __restrict__ hpub) {
  const int tid = threadIdx.x;
  if (blockIdx.x < 4096) {
    int id = blockIdx.x * 256 + tid;
    int gx = id & 31;          // granule within row (32 x 8 bf16 = 256)
    int b  = (id >> 5) & 63;
    int t  = id >> 11;
    int idx = sent[b * T_ + t];            // sentence is [B][T]
    const float* src = emb + (size_t)idx * E_ + gx * 8;
    bf16x8 v;
#pragma unroll
    for (int j = 0; j < 8; ++j) v[j] = (__bf16)src[j];
    int gs = gx ^ (b & 7);                 // XOR swizzle keyed by batch row
    *(bf16x8*)(xs_g + (size_t)(t * 64 + b) * E_ + gs * 8) = v;
    return;
  }
  int bid = blockIdx.x - 4096;       // [0,1536): ((d*16+us)*8+wv)*6 + jg
  {
    int zid = bid * 256 + tid;
    if (zid < 131072) hpub[zid] = 0u;  // clear epochs every call (re-poison safety)
  }
  int jg = bid % 6;
  int wv = (bid / 6) & 7;
  int us = (bid / 48) & 15;
  int d  = bid / 768;
  int j    = jg * 4 + (tid >> 6);
  int lane = tid & 63;
  int c    = wv * 16 + (lane & 15);   // slice row 0..127
  int ul   = c >> 2, gate = c & 3;
  int n    = gate * 512 + us * 32 + ul;
  int k0   = j * 32 + (lane >> 4) * 8;
  const float* Wx = d ? Wx_b : Wx_f;
  const float* Wh = d ? Wh_b : Wh_f;
  bf16x8 v;
#pragma unroll
  for (int e = 0; e < 8; ++e) {
    int k = k0 + e;
    float f = (k < 256) ? Wx[(size_t)k * 2048 + n] : Wh[(size_t)(k - 256) * 2048 + n];
    v[e] = (__bf16)f;
  }
  size_t og = ((size_t)((d * 16 + us) * 8 + wv) * 24 + j) * 64 + lane;
  *(bf16x8*)(w2 + og * 8) = v;
}

// Persistent bidirectional LSTM. 128 WGs x 512 thr.
// Quarter-to-XCD mapping: quarter = wg & 7 (dir = q7>>2, q = q7&3), us = wg>>3.
// Under round-robin block->XCD dispatch all 16 WGs of a quarter share one XCD,
// so the h exchange is XCD-L2-local. Fast path: initial spec loads are sc0
// (L1-bypass, L2 scope). All retries use agent-scope atomics -> correctness
// never depends on placement.
// hpub slice word = ul*16 + b (= wv*64+lane for the producer thread).
__global__ void __launch_bounds__(512)
lstm_main(const __bf16* __restrict__ xs_g, const __bf16* __restrict__ w2,
          u32* __restrict__ hpub, float* __restrict__ hfin,
          const float* __restrict__ b_f, const float* __restrict__ b_b) {
  __shared__ __align__(16) __bf16 xbuf[2][16 * 256];   // 2 x 8 KiB
  __shared__ __align__(16) __bf16 hbuf[16 * 512];      // 16 KiB

  const int wg   = blockIdx.x;
  const int q7   = wg & 7;             // quarter id -> XCD (round-robin)
  const int dir  = q7 >> 2;
  const int q    = q7 & 3;
  const int us   = wg >> 3;            // 0..15
  const int tid  = threadIdx.x;
  const int wv   = tid >> 6;
  const int lane = tid & 63;
  const int bq_l = lane & 15;          // local batch / D col
  const int kq   = lane >> 4;          // k-quarter
  const int bsw  = bq_l & 7;           // swizzle key
  const int ul_own = wv * 4 + kq;      // owned local unit (0..31)
  const int u_own  = us * 32 + ul_own;
  const int b_own  = q * 16 + bq_l;

  // ---- weight fragments: direct coalesced global->reg ----
  bf16x8 wfrag[24];
  {
    const bf16x8* wp = (const bf16x8*)w2 +
                       ((size_t)((dir * 16 + us) * 8 + wv) * 24) * 64 + lane;
#pragma unroll
    for (int j = 0; j < 24; ++j) wfrag[j] = wp[j * 64];
  }

  const float* bias = dir ? b_b : b_f;
  const float bi  = bias[u_own];
  const float bff = bias[512 + u_own];
  const float bg  = bias[1024 + u_own];
  const float bo  = bias[1536 + u_own];
  float c_st = 0.f;

  // ---- slice bases: SB(dir,par,q,us) = (((dir*2+par)*4+q)*16+us)*512 words ----
  u32* const pw0 = hpub + ((size_t)(((dir * 2 + 0) * 4 + q) * 16 + us)) * 512 +
                   wv * 64 + lane;                     // parity: +32768 words

  // ---- consumer: half-wave covers producer us_p's 2KB slice ----
  const int us_p  = 2 * wv + (lane >> 5);
  const int lane5 = lane & 31;
  const u64* const cs0 = (const u64*)(hpub +
      ((size_t)(((dir * 2 + 0) * 4 + q) * 16 + us_p)) * 512) + lane5;
  const u64* const cs1 = cs0 + 16384;   // parity stride = 32768 u32 = 16384 u64
  // u64 j covers words (u = us_p*32 + j*4 + (lane5>>3), b = 2*(lane5&7), +1)
  const int cc = lane5 >> 3;
  const int cb0 = 2 * (lane5 & 7);
  const int cb1 = cb0 + 1;
  int cd0[8], cd1[8];
#pragma unroll
  for (int j = 0; j < 8; ++j) {
    int u = us_p * 32 + j * 4 + cc;    // global unit within quarter's 512
    int g = u >> 3;
    cd0[j] = cb0 * 1024 + ((g ^ (cb0 & 7)) << 4) + ((u & 7) << 1);
    cd1[j] = cb1 * 1024 + ((g ^ (cb1 & 7)) << 4) + ((u & 7) << 1);
  }

  // ---- stage x_0 (8 KiB: 512 granules, 1 per thread) ----
  {
    int t0 = dir ? (T_ - 1) : 0;
    const uint4* xsrc = (const uint4*)(xs_g + ((size_t)t0 * 64 + q * 16) * 256);
    ((uint4*)xbuf[0])[tid] = xsrc[tid];
  }
  __syncthreads();

  for (int t = 0;; ++t) {
    const bool lastt = (t == T_ - 1);
    // ---- [P] speculative h loads: sc0 fast path (XCD-L2-local when the
    //      quarter shares an XCD). Retries below use agent atomics. ----
    u64 v[8];
    const u64* csrc = (t & 1) ? cs1 : cs0;
    if (t > 0) {
      asm volatile(
          "global_load_dwordx2 %[o0], %[a], off sc0\n\t"
          "global_load_dwordx2 %[o1], %[a], off offset:256 sc0\n\t"
          "global_load_dwordx2 %[o2], %[a], off offset:512 sc0\n\t"
          "global_load_dwordx2 %[o3], %[a], off offset:768 sc0\n\t"
          "global_load_dwordx2 %[o4], %[a], off offset:1024 sc0\n\t"
          "global_load_dwordx2 %[o5], %[a], off offset:1280 sc0\n\t"
          "global_load_dwordx2 %[o6], %[a], off offset:1536 sc0\n\t"
          "global_load_dwordx2 %[o7], %[a], off offset:1792 sc0"
          : [o0] "=&v"(v[0]), [o1] "=&v"(v[1]), [o2] "=&v"(v[2]),
            [o3] "=&v"(v[3]), [o4] "=&v"(v[4]), [o5] "=&v"(v[5]),
            [o6] "=&v"(v[6]), [o7] "=&v"(v[7])
          : [a] "v"(csrc)
          : "memory");
    }
    // ---- issue x_{t+1} global load early (consumed after publish) ----
    uint4 xg;
    if (!lastt) {
      const int teff = dir ? (T_ - 2 - t) : (t + 1);
      xg = ((const uint4*)(xs_g + ((size_t)teff * 64 + q * 16) * 256))[tid];
    }

    // ---- [A] x-part MFMAs ----
    f32x4 acc0 = {0.f, 0.f, 0.f, 0.f};
    f32x4 acc1 = {0.f, 0.f, 0.f, 0.f};
    const __bf16* xb = xbuf[t & 1];
#pragma unroll
    for (int j = 0; j < 8; ++j) {
      int g = j * 4 + kq;
      bf16x8 a = *(const bf16x8*)(xb + bq_l * 256 + ((g ^ bsw) << 3));
      if (j & 1) acc1 = __builtin_amdgcn_mfma_f32_16x16x32_bf16(wfrag[j], a, acc1, 0, 0, 0);
      else       acc0 = __builtin_amdgcn_mfma_f32_16x16x32_bf16(wfrag[j], a, acc0, 0, 0, 0);
    }

    if (t > 0) {
      // ---- make the asm loads' results visible to the validate below ----
      asm volatile("s_waitcnt vmcnt(0)" ::: "memory");
      __builtin_amdgcn_sched_barrier(0);
      // ---- [B] validate embedded epochs; retry (agent atomics) on miss ----
      const u32 ep = (u32)t;
      for (;;) {
        u32 bad = 0;
#pragma unroll
        for (int j = 0; j < 8; ++j)
          bad |= ((u32)v[j] ^ ep) | ((u32)(v[j] >> 32) ^ ep);
        bad &= 0xFFFFu;
        if (!__any((int)bad)) break;
        __builtin_amdgcn_s_sleep(1);
#pragma unroll
        for (int j = 0; j < 8; ++j)
          v[j] = __hip_atomic_load(csrc + j * 32, __ATOMIC_RELAXED, __HIP_MEMORY_SCOPE_AGENT);
      }
      // ---- [C] pack hi16s -> swizzled hbuf (16 x ds_write_b16) ----
#pragma unroll
      for (int j = 0; j < 8; ++j) {
        *(u16*)((char*)hbuf + cd0[j]) = (u16)(v[j] >> 16);
        *(u16*)((char*)hbuf + cd1[j]) = (u16)(v[j] >> 48);
      }
      // ---- S1: raw barrier, LDS-only drain (xg stays in flight) ----
      asm volatile("s_waitcnt lgkmcnt(0)" ::: "memory");
      __builtin_amdgcn_sched_barrier(0);
      __builtin_amdgcn_s_barrier();
      __builtin_amdgcn_sched_barrier(0);
      // ---- [D] h-part MFMAs ----
#pragma unroll
      for (int j = 0; j < 16; ++j) {
        int g = j * 4 + kq;
        bf16x8 a = *(const bf16x8*)(hbuf + bq_l * 512 + ((g ^ bsw) << 3));
        if (j & 1) acc1 = __builtin_amdgcn_mfma_f32_16x16x32_bf16(wfrag[8 + j], a, acc1, 0, 0, 0);
        else       acc0 = __builtin_amdgcn_mfma_f32_16x16x32_bf16(wfrag[8 + j], a, acc0, 0, 0, 0);
      }
    }

    // ---- gates in registers ----
    const float zi = acc0[0] + acc1[0] + bi;
    const float zf = acc0[1] + acc1[1] + bff;
    const float zg = acc0[2] + acc1[2] + bg;
    const float zo = acc0[3] + acc1[3] + bo;
    c_st = fsigm(zf) * c_st + fsigm(zi) * ftanh(zg);
    const float hv = fsigm(zo) * ftanh(c_st);

    if (lastt) {
      hfin[(size_t)dir * 32768 + b_own * 512 + u_own] = hv;
      break;
    }

    // ---- [E] publish own word (coalesced agent atomic) ----
    {
      union { __bf16 h; u16 s; } cv;
      cv.h = (__bf16)hv;
      u32 word = ((u32)cv.s << 16) | (u32)(t + 1);
      __hip_atomic_store(pw0 + ((t + 1) & 1) * 32768, word, __ATOMIC_RELAXED,
                         __HIP_MEMORY_SCOPE_AGENT);
    }
    // ---- complete x_{t+1} staging (load already in flight) ----
    ((uint4*)xbuf[(t + 1) & 1])[tid] = xg;
    // ---- S2: full syncthreads — vmcnt(0) drain COMMITS the publish to the
    //      coherence point before any wave proceeds (the r7 win; keep). ----
    __syncthreads();
  }
}

// Final head, parallel: 64 blocks (one per batch row) x 256 threads.
__global__ void __launch_bounds__(256)
dense_kernel(const float* __restrict__ hfin, const float* __restrict__ W1,
             const float* __restrict__ b1, const float* __restrict__ W2,
             const float* __restrict__ b2, float* __restrict__ out) {
  __shared__ float part[4][64];
  __shared__ float hw[64];
  const int b   = blockIdx.x;
  const int tid = threadIdx.x;
  const int kc  = tid >> 6;        // k-chunk 0..3
  const int j   = tid & 63;        // hidden col
  float a = (kc == 0) ? b1[j] : 0.f;
#pragma unroll 4
  for (int k = kc * 256; k < kc * 256 + 256; ++k) {
    const float hv = hfin[(size_t)(k >> 9) * 32768 + b * 512 + (k & 511)];
    a += hv * W1[(size_t)k * 64 + j];
  }
  part[kc][j] = a;
  __syncthreads();
  if (tid < 64)
    hw[tid] = (part[0][tid] + part[1][tid] + part[2][tid] + part[3][tid]) * W2[tid];
  __syncthreads();
  if (tid == 0) {
    float l = b2[0];
#pragma unroll 8
    for (int i = 0; i < 64; ++i) l += hw[i];
    out[b] = 1.f / (1.f + __expf(-l));
  }
}

extern "C" void kernel_launch(void* const* d_in, const int* in_sizes, int n_in,
                              void* d_out, int out_size, void* d_ws, size_t ws_size,
                              hipStream_t stream) {
  const int*   sent = (const int*)d_in[0];
  const float* emb  = (const float*)d_in[1];
  const float* Wx_f = (const float*)d_in[2];
  const float* Wh_f = (const float*)d_in[3];
  const float* b_f  = (const float*)d_in[4];
  const float* Wx_b = (const float*)d_in[5];
  const float* Wh_b = (const float*)d_in[6];
  const float* b_b  = (const float*)d_in[7];
  const float* W1   = (const float*)d_in[8];
  const float* b1   = (const float*)d_in[9];
  const float* W2   = (const float*)d_in[10];
  const float* b2   = (const float*)d_in[11];
  float* out = (float*)d_out;

  char* ws = (char*)d_ws;
  __bf16* xs_g = (__bf16*)(ws + WS_XS);
  __bf16* w2   = (__bf16*)(ws + WS_W2);
  u32*    hpub = (u32*)(ws + WS_HP);
  float*  hfin = (float*)(ws + WS_HF);

  hipLaunchKernelGGL(prep_kernel, dim3(5632), dim3(256), 0, stream,
                     sent, emb, xs_g, Wx_f, Wh_f, Wx_b, Wh_b, w2, hpub);

  void* args[] = {(void*)&xs_g, (void*)&w2, (void*)&hpub, (void*)&hfin,
                  (void*)&b_f, (void*)&b_b};
  hipLaunchCooperativeKernel((void*)lstm_main, dim3(128), dim3(512), args, 0, stream);

  hipLaunchKernelGGL(dense_kernel, dim3(64), dim3(256), 0, stream,
                     hfin, W1, b1, W2, b2, out);
}